// Round 9
// baseline (241.674 us; speedup 1.0000x reference)
//
#include <hip/hip_runtime.h>
#include <hip/hip_bf16.h>

#define EPS 1e-5f
#define SCALE 0.17677669529663687f    // 32^-0.5
#define QSCALE 0.25500526817095634f   // SCALE * log2(e): attn uses exp2

typedef __attribute__((ext_vector_type(8))) short bf16x8;
typedef __attribute__((ext_vector_type(4))) float f32x4;
typedef __attribute__((ext_vector_type(8))) unsigned short u16x8;

__device__ __forceinline__ unsigned short f2bf(float x) {
  union { float f; unsigned int u; } a; a.f = x;
  unsigned int r = a.u + 0x7FFFu + ((a.u >> 16) & 1u);
  return (unsigned short)(r >> 16);
}
__device__ __forceinline__ float bf2f(unsigned short u) {
  union { unsigned int u; float f; } a; a.u = ((unsigned int)u) << 16;
  return a.f;
}

// async global->LDS, 16 B per lane; lds base wave-uniform, HW writes lane i
// at ldsbase + i*16 (guide §5 / m97).
__device__ __forceinline__ void gload_lds16(const void* g, void* l) {
  __builtin_amdgcn_global_load_lds(
      (const __attribute__((address_space(1))) unsigned int*)g,
      (__attribute__((address_space(3))) unsigned int*)l, 16, 0, 0);
}

// pack high halves of two f32 -> [hi16(b) : hi16(a)] (truncation, 1 v_perm)
__device__ __forceinline__ unsigned int pack_bf_trunc(float a, float b) {
  return __builtin_amdgcn_perm(__float_as_uint(b), __float_as_uint(a), 0x07060302u);
}

// ---------------------------------------------------------------------------
// Cast qkv_w (1024x512) and proj_w (512x512) fp32 -> bf16, same layout.
// ---------------------------------------------------------------------------
__global__ __launch_bounds__(256) void cast_w_kernel(
    const float* __restrict__ qw, const float* __restrict__ pw,
    short* __restrict__ wq, short* __restrict__ wp) {
  int idx = blockIdx.x * 256 + threadIdx.x;
  const float4* src;
  ushort4* dst;
  if (idx < 131072) {
    src = (const float4*)qw + idx;
    dst = (ushort4*)wq + idx;
  } else {
    src = (const float4*)pw + (idx - 131072);
    dst = (ushort4*)wp + (idx - 131072);
  }
  float4 v = *src;
  ushort4 u;
  u.x = f2bf(v.x); u.y = f2bf(v.y); u.z = f2bf(v.z); u.w = f2bf(v.w);
  *dst = u;
}

// ---------------------------------------------------------------------------
// Transpose-cast X (B,512,1600) fp32 -> XT (B,1600,512) bf16. 64x64 LDS tile.
// ---------------------------------------------------------------------------
__global__ __launch_bounds__(256) void transpose_cast_kernel(
    const float* __restrict__ X, short* __restrict__ XT) {
  __shared__ unsigned short T[64][72];
  const int b = blockIdx.z, c0 = blockIdx.x * 64, n0 = blockIdx.y * 64;
  const int t = threadIdx.x, nl = t & 63, w = t >> 6;
#pragma unroll
  for (int ci = 0; ci < 16; ++ci) {
    int cl = ci * 4 + w;
    T[nl][cl] = f2bf(X[((size_t)(b * 512 + c0 + cl)) * 1600 + n0 + nl]);
  }
  __syncthreads();
  const int n2 = t >> 2, cg = (t & 3) * 16;
  unsigned short* o = (unsigned short*)XT + ((size_t)(b * 1600 + n0 + n2)) * 512 + c0 + cg;
  *(u16x8*)&o[0] = *(const u16x8*)&T[n2][cg];
  *(u16x8*)&o[8] = *(const u16x8*)&T[n2][cg + 8];
}

// ---------------------------------------------------------------------------
// Transpose bf16 (B,512,1600) -> (B,1600,512). Same 64x64 LDS tile pattern.
// ---------------------------------------------------------------------------
__global__ __launch_bounds__(256) void transpose16_kernel(
    const short* __restrict__ S, short* __restrict__ D) {
  __shared__ unsigned short T[64][72];
  const int b = blockIdx.z, c0 = blockIdx.x * 64, n0 = blockIdx.y * 64;
  const int t = threadIdx.x, nl = t & 63, w = t >> 6;
  const unsigned short* Sp = (const unsigned short*)S;
#pragma unroll
  for (int ci = 0; ci < 16; ++ci) {
    int cl = ci * 4 + w;
    T[nl][cl] = Sp[((size_t)(b * 512 + c0 + cl)) * 1600 + n0 + nl];
  }
  __syncthreads();
  const int n2 = t >> 2, cg = (t & 3) * 16;
  unsigned short* o = (unsigned short*)D + ((size_t)(b * 1600 + n0 + n2)) * 512 + c0 + cg;
  *(u16x8*)&o[0] = *(const u16x8*)&T[n2][cg];
  *(u16x8*)&o[8] = *(const u16x8*)&T[n2][cg + 8];
}

// ---------------------------------------------------------------------------
// QKV GEMM v3 (m97 structure, unchanged except q pre-scale now QSCALE).
// ---------------------------------------------------------------------------
__global__ __launch_bounds__(256) void qkv_mfma_kernel(
    const short* __restrict__ XT, const short* __restrict__ WQ,
    const float* __restrict__ gamma, const float* __restrict__ beta,
    const float* __restrict__ mean, const float* __restrict__ var,
    short* __restrict__ qT, short* __restrict__ kT, short* __restrict__ vb) {
  __shared__ __align__(16) unsigned short As[128 * 32];
  __shared__ __align__(16) unsigned short Bs[128 * 32];

  const int t = threadIdx.x, w = t >> 6, lane = t & 63;
  const int quad = lane >> 4, l16 = lane & 15;
  const int wr = w >> 1, wc = w & 1;
  const int ngt = blockIdx.x, h = blockIdx.y;
  const int o0 = h * 128, ng0 = ngt * 128;

  const int srow = lane >> 2;
  const int sseg = (lane & 3) * 8;

  f32x4 acc[4][4];
#pragma unroll
  for (int mi = 0; mi < 4; ++mi)
#pragma unroll
    for (int nj = 0; nj < 4; ++nj) { acc[mi][nj][0]=0.f; acc[mi][nj][1]=0.f; acc[mi][nj][2]=0.f; acc[mi][nj][3]=0.f; }

  for (int kt = 0; kt < 16; ++kt) {
    const int c0 = kt * 32;
    if (kt) __syncthreads();
#pragma unroll
    for (int r = 0; r < 2; ++r) {
      const int row = (r * 4 + w) * 16 + srow;
      gload_lds16(WQ + (size_t)(o0 + row) * 512 + c0 + sseg, As + (r * 4 + w) * 512);
      gload_lds16(XT + (size_t)(ng0 + row) * 512 + c0 + sseg, Bs + (r * 4 + w) * 512);
    }
    __syncthreads();
    bf16x8 af[4], bfr[4];
#pragma unroll
    for (int i = 0; i < 4; ++i) {
      af[i]  = *(const bf16x8*)&As[(wr * 64 + i * 16 + l16) * 32 + quad * 8];
      bfr[i] = *(const bf16x8*)&Bs[(wc * 64 + i * 16 + l16) * 32 + quad * 8];
    }
#pragma unroll
    for (int mi = 0; mi < 4; ++mi)
#pragma unroll
      for (int nj = 0; nj < 4; ++nj)
        acc[mi][nj] = __builtin_amdgcn_mfma_f32_16x16x32_bf16(af[mi], bfr[nj], acc[mi][nj], 0, 0, 0);
  }

  const int ng_base = ng0 + wc * 64;
#pragma unroll
  for (int mi = 0; mi < 4; ++mi) {
    const int ol = wr * 64 + mi * 16 + quad * 4;
    const int ob = o0 + ol;
    float inv[4], add[4];
#pragma unroll
    for (int r = 0; r < 4; ++r) {
      inv[r] = gamma[ob + r] * rsqrtf(var[ob + r] + EPS);
      add[r] = beta[ob + r] - mean[ob + r] * inv[r];
    }
    const int region = wr * 2 + (mi >> 1);   // 0=q, 1=k, 2/3=v
    if (region == 0) {
      const int kk = mi * 16 + quad * 4;
#pragma unroll
      for (int nj = 0; nj < 4; ++nj) {
        int ng = ng_base + nj * 16 + l16;
        int b = ng / 1600, n = ng - b * 1600;
        ushort4 u;
        u.x = f2bf((acc[mi][nj][0] * inv[0] + add[0]) * QSCALE);
        u.y = f2bf((acc[mi][nj][1] * inv[1] + add[1]) * QSCALE);
        u.z = f2bf((acc[mi][nj][2] * inv[2] + add[2]) * QSCALE);
        u.w = f2bf((acc[mi][nj][3] * inv[3] + add[3]) * QSCALE);
        *(ushort4*)&qT[((size_t)(b * 8 + h) * 1600 + n) * 32 + kk] = u;
      }
    } else if (region == 1) {
      const int kk = (mi - 2) * 16 + quad * 4;
#pragma unroll
      for (int nj = 0; nj < 4; ++nj) {
        int ng = ng_base + nj * 16 + l16;
        int b = ng / 1600, n = ng - b * 1600;
        ushort4 u;
        u.x = f2bf(acc[mi][nj][0] * inv[0] + add[0]);
        u.y = f2bf(acc[mi][nj][1] * inv[1] + add[1]);
        u.z = f2bf(acc[mi][nj][2] * inv[2] + add[2]);
        u.w = f2bf(acc[mi][nj][3] * inv[3] + add[3]);
        *(ushort4*)&kT[((size_t)(b * 8 + h) * 1600 + n) * 32 + kk] = u;
      }
    } else {
      const int ch = h * 64 + (ol - 64);
#pragma unroll
      for (int nj = 0; nj < 4; ++nj) {
        int ng = ng_base + nj * 16 + l16;
        int b = ng / 1600, n = ng - b * 1600;
#pragma unroll
        for (int r = 0; r < 4; ++r)
          ((unsigned short*)vb)[((size_t)(b * 512 + ch + r)) * 1600 + n] =
              f2bf(acc[mi][nj][r] * inv[r] + add[r]);
      }
    }
  }
}

// ---------------------------------------------------------------------------
// MFMA flash attention v4: q pre-scaled into log2 domain -> exp2 (1 instr);
// P packed by v_perm truncation (1 instr / 2 vals); y written as bf16.
// S^T layout, double-buffered P, 1 barrier/m-tile, grid.x = bh.
// ---------------------------------------------------------------------------
__global__ __launch_bounds__(256) void attn_mfma_kernel(
    const short* __restrict__ qT, const short* __restrict__ kT,
    const short* __restrict__ vb, short* __restrict__ ybf) {
  const int N = 1600;
  const int PS = 72;
  __shared__ __align__(16) unsigned short Plds[2][64 * PS];
  __shared__ float den_lds[4][64];
  __shared__ float rden[64];

  const int t = threadIdx.x;
  const int w = t >> 6, lane = t & 63, quad = lane >> 4, l16 = lane & 15;
  const int bh = blockIdx.x, b = bh >> 3, h = bh & 7;
  const int n0 = blockIdx.y * 64;

  const short* qTb = qT + (size_t)(b * 8 + h) * N * 32;
  const short* kTb = kT + (size_t)(b * 8 + h) * N * 32;
  const short* vbb = vb + ((size_t)b * 512 + h * 64 + w * 16) * N;

  bf16x8 qf[4];
#pragma unroll
  for (int i = 0; i < 4; ++i)
    qf[i] = *(const bf16x8*)(qTb + (size_t)(n0 + i * 16 + l16) * 32 + quad * 8);

  f32x4 acc[4];
#pragma unroll
  for (int i = 0; i < 4; ++i) { acc[i][0]=0.f; acc[i][1]=0.f; acc[i][2]=0.f; acc[i][3]=0.f; }
  float den[4] = {0.f, 0.f, 0.f, 0.f};
  const f32x4 zero4 = {0.f, 0.f, 0.f, 0.f};

#pragma unroll 2
  for (int mt = 0; mt < 25; ++mt) {
    const int m0 = mt * 64;
    unsigned short* Pb = &Plds[mt & 1][0];
    bf16x8 kf = *(const bf16x8*)(kTb + (size_t)(m0 + w * 16 + l16) * 32 + quad * 8);
#pragma unroll
    for (int i = 0; i < 4; ++i) {
      f32x4 s = __builtin_amdgcn_mfma_f32_16x16x32_bf16(kf, qf[i], zero4, 0, 0, 0);
      float p0 = exp2f(s[0]), p1 = exp2f(s[1]), p2 = exp2f(s[2]), p3 = exp2f(s[3]);
      den[i] += (p0 + p1) + (p2 + p3);
      uint2 pk;
      pk.x = pack_bf_trunc(p0, p1);
      pk.y = pack_bf_trunc(p2, p3);
      *(uint2*)&Pb[(size_t)(i * 16 + l16) * PS + w * 16 + quad * 4] = pk;
    }
    __syncthreads();
#pragma unroll
    for (int c = 0; c < 2; ++c) {
      bf16x8 vfr = *(const bf16x8*)(vbb + (size_t)l16 * N + m0 + c * 32 + quad * 8);
#pragma unroll
      for (int i = 0; i < 4; ++i) {
        bf16x8 pf = *(const bf16x8*)(Pb + (size_t)(i * 16 + l16) * PS + c * 32 + quad * 8);
        acc[i] = __builtin_amdgcn_mfma_f32_16x16x32_bf16(pf, vfr, acc[i], 0, 0, 0);
      }
    }
  }

#pragma unroll
  for (int i = 0; i < 4; ++i) {
    den[i] += __shfl_xor(den[i], 16, 64);
    den[i] += __shfl_xor(den[i], 32, 64);
  }
  if (quad == 0) {
#pragma unroll
    for (int i = 0; i < 4; ++i)
      den_lds[w][i * 16 + l16] = den[i];
  }
  __syncthreads();
  if (t < 64)
    rden[t] = 1.f / (den_lds[0][t] + den_lds[1][t] + den_lds[2][t] + den_lds[3][t]);
  __syncthreads();

  // lane owns channel h*64 + w*16 + l16; bf16 output (rounded), 8B stores
  unsigned short* yr = (unsigned short*)ybf +
      ((size_t)b * 512 + h * 64 + w * 16 + l16) * N + n0;
#pragma unroll
  for (int i = 0; i < 4; ++i) {
    const int nb = i * 16 + quad * 4;
    ushort4 o4;
    o4.x = f2bf(acc[i][0] * rden[nb + 0]);
    o4.y = f2bf(acc[i][1] * rden[nb + 1]);
    o4.z = f2bf(acc[i][2] * rden[nb + 2]);
    o4.w = f2bf(acc[i][3] * rden[nb + 3]);
    *(ushort4*)&yr[nb] = o4;
  }
}

// ---------------------------------------------------------------------------
// PE v4: reads attention y as bf16, LDS-staged depthwise 3x3 + BN + add,
// natural-layout bf16 output.
// ---------------------------------------------------------------------------
__global__ __launch_bounds__(256) void pe_kernel(
    const short* __restrict__ Ybf, const short* __restrict__ VB,
    const float* __restrict__ pw,
    const float* __restrict__ gamma, const float* __restrict__ beta,
    const float* __restrict__ mean, const float* __restrict__ var,
    short* __restrict__ YB) {
  __shared__ __align__(16) unsigned short V[4 * 42 * 56];
  __shared__ float wlds[36];
  __shared__ float invs[4], adds[4];

  const int t = threadIdx.x;
  const int b = blockIdx.y, c0 = blockIdx.x * 4;

  const u16x8 z = {0, 0, 0, 0, 0, 0, 0, 0};
  for (int k = t; k < 1176; k += 256)
    *(u16x8*)&V[k * 8] = z;
  if (t < 36) wlds[t] = pw[c0 * 9 + t];
  if (t < 4) {
    int c = c0 + t;
    float inv = gamma[c] * rsqrtf(var[c] + EPS);
    invs[t] = inv;
    adds[t] = beta[c] - mean[c] * inv;
  }
  __syncthreads();

  for (int u = t; u < 800; u += 256) {
    int ch = u / 200, j = u - ch * 200;
    int row = j / 5, col8 = (j - row * 5) * 8;
    u16x8 d = *(const u16x8*)((const unsigned short*)VB +
        ((size_t)(b * 512 + c0 + ch) * 1600 + row * 40 + col8));
    *(u16x8*)&V[ch * 2352 + (row + 1) * 56 + 8 + col8] = d;
  }
  __syncthreads();

#pragma unroll 1
  for (int k = 0; k < 25; ++k) {
    int o = k * 256 + t;
    int ch = o / 1600, n = o - ch * 1600;
    int hh = n / 40, ww = n - hh * 40;
    const unsigned short* Vc = &V[ch * 2352 + (hh + 1) * 56 + 8 + ww];
    const float* wk = &wlds[ch * 9];
    float s = 0.f;
#pragma unroll
    for (int dy = 0; dy < 3; ++dy)
#pragma unroll
      for (int dx = 0; dx < 3; ++dx)
        s += wk[dy * 3 + dx] * bf2f(Vc[(dy - 1) * 56 + (dx - 1)]);
    size_t idx = (size_t)(b * 512 + c0 + ch) * 1600 + n;
    float val = bf2f(((const unsigned short*)Ybf)[idx]) + s * invs[ch] + adds[ch];
    YB[idx] = (short)f2bf(val);
  }
}

// ---------------------------------------------------------------------------
// Proj GEMM v3 (m97 structure, unchanged).
// ---------------------------------------------------------------------------
__global__ __launch_bounds__(256) void proj_mfma_kernel(
    const short* __restrict__ YT, const short* __restrict__ WP,
    const float* __restrict__ gamma, const float* __restrict__ beta,
    const float* __restrict__ mean, const float* __restrict__ var,
    float* __restrict__ OUT) {
  __shared__ __align__(16) unsigned short As[64 * 32];
  __shared__ __align__(16) unsigned short Bs[128 * 32];

  const int t = threadIdx.x, w = t >> 6, lane = t & 63;
  const int quad = lane >> 4, l16 = lane & 15;
  const int wr = w >> 1, wc = w & 1;
  const int ngt = blockIdx.x;
  const int o0 = blockIdx.y * 64;
  const int ng0 = ngt * 128;

  const int srow = lane >> 2;
  const int sseg = (lane & 3) * 8;

  f32x4 acc[2][4];
#pragma unroll
  for (int mi = 0; mi < 2; ++mi)
#pragma unroll
    for (int nj = 0; nj < 4; ++nj) { acc[mi][nj][0]=0.f; acc[mi][nj][1]=0.f; acc[mi][nj][2]=0.f; acc[mi][nj][3]=0.f; }

  for (int kt = 0; kt < 16; ++kt) {
    const int c0 = kt * 32;
    if (kt) __syncthreads();
    {
      const int row = w * 16 + srow;
      gload_lds16(WP + (size_t)(o0 + row) * 512 + c0 + sseg, As + w * 512);
    }
#pragma unroll
    for (int r = 0; r < 2; ++r) {
      const int row = (r * 4 + w) * 16 + srow;
      gload_lds16(YT + (size_t)(ng0 + row) * 512 + c0 + sseg, Bs + (r * 4 + w) * 512);
    }
    __syncthreads();
    bf16x8 af[2], bfr[4];
#pragma unroll
    for (int i = 0; i < 2; ++i)
      af[i] = *(const bf16x8*)&As[(wr * 32 + i * 16 + l16) * 32 + quad * 8];
#pragma unroll
    for (int i = 0; i < 4; ++i)
      bfr[i] = *(const bf16x8*)&Bs[(wc * 64 + i * 16 + l16) * 32 + quad * 8];
#pragma unroll
    for (int mi = 0; mi < 2; ++mi)
#pragma unroll
      for (int nj = 0; nj < 4; ++nj)
        acc[mi][nj] = __builtin_amdgcn_mfma_f32_16x16x32_bf16(af[mi], bfr[nj], acc[mi][nj], 0, 0, 0);
  }

  const int ng_base = ng0 + wc * 64;
#pragma unroll
  for (int mi = 0; mi < 2; ++mi) {
    const int ob = o0 + wr * 32 + mi * 16 + quad * 4;
    float inv[4], add[4];
#pragma unroll
    for (int r = 0; r < 4; ++r) {
      inv[r] = gamma[ob + r] * rsqrtf(var[ob + r] + EPS);
      add[r] = beta[ob + r] - mean[ob + r] * inv[r];
    }
#pragma unroll
    for (int nj = 0; nj < 4; ++nj) {
      int ng = ng_base + nj * 16 + l16;
      int b = ng / 1600, n = ng - b * 1600;
#pragma unroll
      for (int r = 0; r < 4; ++r)
        OUT[((size_t)(b * 512 + ob + r)) * 1600 + n] = acc[mi][nj][r] * inv[r] + add[r];
    }
  }
}

// ---------------------------------------------------------------------------
extern "C" void kernel_launch(void* const* d_in, const int* in_sizes, int n_in,
                              void* d_out, int out_size, void* d_ws, size_t ws_size,
                              hipStream_t stream) {
  const float* x          = (const float*)d_in[0];
  const float* qkv_w      = (const float*)d_in[1];
  const float* qkv_gamma  = (const float*)d_in[2];
  const float* qkv_beta   = (const float*)d_in[3];
  const float* qkv_mean   = (const float*)d_in[4];
  const float* qkv_var    = (const float*)d_in[5];
  const float* pe_w       = (const float*)d_in[6];
  const float* pe_gamma   = (const float*)d_in[7];
  const float* pe_beta    = (const float*)d_in[8];
  const float* pe_mean    = (const float*)d_in[9];
  const float* pe_var     = (const float*)d_in[10];
  const float* proj_w     = (const float*)d_in[11];
  const float* proj_gamma = (const float*)d_in[12];
  const float* proj_beta  = (const float*)d_in[13];
  const float* proj_mean  = (const float*)d_in[14];
  const float* proj_var   = (const float*)d_in[15];
  float* out = (float*)d_out;

  // workspace layout (64 MB region, same as before):
  //   [A] 26,214,400 B : ybf_attn bf16 (B,512,1600) uses first half
  //   qT   bf16 (B,8,1600,32)    6,553,600 B  } dead after attn -> pe out
  //   kT   bf16 (B,8,1600,32)    6,553,600 B  }
  //   vb   bf16 (B,512,1600)    13,107,200 B
  //   xT   bf16 (B,1600,512)    13,107,200 B   (reused as yT)
  //   wq   bf16 (1024,512)       1,048,576 B
  //   wp   bf16 (512,512)          524,288 B
  float* ws_a = (float*)d_ws;
  short* ybf_attn = (short*)d_ws;                 // attn output, bf16 natural
  short* qT   = (short*)(ws_a + (size_t)6553600);
  short* kT   = qT + (size_t)3276800;
  short* vb   = kT + (size_t)3276800;
  short* xT   = vb + (size_t)6553600;
  short* wq   = xT + (size_t)6553600;
  short* wp   = wq + (size_t)524288;
  short* yT   = xT;
  short* ybf_pe = qT;                             // pe output (qT/kT dead)

  cast_w_kernel<<<768, 256, 0, stream>>>(qkv_w, proj_w, wq, wp);
  {
    dim3 grid(8, 25, 8), block(256);
    transpose_cast_kernel<<<grid, block, 0, stream>>>(x, xT);
  }
  {
    dim3 grid(100, 8), block(256);
    qkv_mfma_kernel<<<grid, block, 0, stream>>>(
        xT, wq, qkv_gamma, qkv_beta, qkv_mean, qkv_var, qT, kT, vb);
  }
  {
    dim3 grid(64, 25), block(256);
    attn_mfma_kernel<<<grid, block, 0, stream>>>(qT, kT, vb, ybf_attn);
  }
  {
    dim3 grid(128, 8), block(256);
    pe_kernel<<<grid, block, 0, stream>>>(
        ybf_attn, vb, pe_w, pe_gamma, pe_beta, pe_mean, pe_var, ybf_pe);
  }
  {
    dim3 grid(8, 25, 8), block(256);
    transpose16_kernel<<<grid, block, 0, stream>>>(ybf_pe, yT);
  }
  {
    dim3 grid(100, 8), block(256);
    proj_mfma_kernel<<<grid, block, 0, stream>>>(
        yT, wp, proj_gamma, proj_beta, proj_mean, proj_var, out);
  }
}

// Round 10
// 235.294 us; speedup vs baseline: 1.0271x; 1.0271x over previous
//
#include <hip/hip_runtime.h>
#include <hip/hip_bf16.h>

#define EPS 1e-5f
#define SCALE 0.17677669529663687f    // 32^-0.5
#define QSCALE 0.25500526817095634f   // SCALE * log2(e): attn uses exp2

typedef __attribute__((ext_vector_type(8))) short bf16x8;
typedef __attribute__((ext_vector_type(4))) float f32x4;
typedef __attribute__((ext_vector_type(8))) unsigned short u16x8;

__device__ __forceinline__ unsigned short f2bf(float x) {
  union { float f; unsigned int u; } a; a.f = x;
  unsigned int r = a.u + 0x7FFFu + ((a.u >> 16) & 1u);
  return (unsigned short)(r >> 16);
}
__device__ __forceinline__ float bf2f(unsigned short u) {
  union { unsigned int u; float f; } a; a.u = ((unsigned int)u) << 16;
  return a.f;
}

// single-instruction v_exp_f32 (2^x). libm exp2f w/o fast-math lowers to the
// precise OCML sequence (~10 instr) — that was round 9's regression.
__device__ __forceinline__ float fexp2(float x) {
#if __has_builtin(__builtin_amdgcn_exp2f)
  return __builtin_amdgcn_exp2f(x);
#else
  float r; asm("v_exp_f32 %0, %1" : "=v"(r) : "v"(x)); return r;
#endif
}

// async global->LDS, 16 B per lane; lds base wave-uniform, HW writes lane i
// at ldsbase + i*16 (guide §5 / m97).
__device__ __forceinline__ void gload_lds16(const void* g, void* l) {
  __builtin_amdgcn_global_load_lds(
      (const __attribute__((address_space(1))) unsigned int*)g,
      (__attribute__((address_space(3))) unsigned int*)l, 16, 0, 0);
}

// pack high halves of two f32 -> [hi16(b) : hi16(a)] (truncation, 1 v_perm)
__device__ __forceinline__ unsigned int pack_bf_trunc(float a, float b) {
  return __builtin_amdgcn_perm(__float_as_uint(b), __float_as_uint(a), 0x07060302u);
}

// ---------------------------------------------------------------------------
// Cast qkv_w (1024x512) and proj_w (512x512) fp32 -> bf16, same layout.
// ---------------------------------------------------------------------------
__global__ __launch_bounds__(256) void cast_w_kernel(
    const float* __restrict__ qw, const float* __restrict__ pw,
    short* __restrict__ wq, short* __restrict__ wp) {
  int idx = blockIdx.x * 256 + threadIdx.x;
  const float4* src;
  ushort4* dst;
  if (idx < 131072) {
    src = (const float4*)qw + idx;
    dst = (ushort4*)wq + idx;
  } else {
    src = (const float4*)pw + (idx - 131072);
    dst = (ushort4*)wp + (idx - 131072);
  }
  float4 v = *src;
  ushort4 u;
  u.x = f2bf(v.x); u.y = f2bf(v.y); u.z = f2bf(v.z); u.w = f2bf(v.w);
  *dst = u;
}

// ---------------------------------------------------------------------------
// Transpose-cast X (B,512,1600) fp32 -> XT (B,1600,512) bf16. 64x64 LDS tile.
// ---------------------------------------------------------------------------
__global__ __launch_bounds__(256) void transpose_cast_kernel(
    const float* __restrict__ X, short* __restrict__ XT) {
  __shared__ unsigned short T[64][72];
  const int b = blockIdx.z, c0 = blockIdx.x * 64, n0 = blockIdx.y * 64;
  const int t = threadIdx.x, nl = t & 63, w = t >> 6;
#pragma unroll
  for (int ci = 0; ci < 16; ++ci) {
    int cl = ci * 4 + w;
    T[nl][cl] = f2bf(X[((size_t)(b * 512 + c0 + cl)) * 1600 + n0 + nl]);
  }
  __syncthreads();
  const int n2 = t >> 2, cg = (t & 3) * 16;
  unsigned short* o = (unsigned short*)XT + ((size_t)(b * 1600 + n0 + n2)) * 512 + c0 + cg;
  *(u16x8*)&o[0] = *(const u16x8*)&T[n2][cg];
  *(u16x8*)&o[8] = *(const u16x8*)&T[n2][cg + 8];
}

// ---------------------------------------------------------------------------
// Transpose bf16 (B,512,1600) -> (B,1600,512). Same 64x64 LDS tile pattern.
// ---------------------------------------------------------------------------
__global__ __launch_bounds__(256) void transpose16_kernel(
    const short* __restrict__ S, short* __restrict__ D) {
  __shared__ unsigned short T[64][72];
  const int b = blockIdx.z, c0 = blockIdx.x * 64, n0 = blockIdx.y * 64;
  const int t = threadIdx.x, nl = t & 63, w = t >> 6;
  const unsigned short* Sp = (const unsigned short*)S;
#pragma unroll
  for (int ci = 0; ci < 16; ++ci) {
    int cl = ci * 4 + w;
    T[nl][cl] = Sp[((size_t)(b * 512 + c0 + cl)) * 1600 + n0 + nl];
  }
  __syncthreads();
  const int n2 = t >> 2, cg = (t & 3) * 16;
  unsigned short* o = (unsigned short*)D + ((size_t)(b * 1600 + n0 + n2)) * 512 + c0 + cg;
  *(u16x8*)&o[0] = *(const u16x8*)&T[n2][cg];
  *(u16x8*)&o[8] = *(const u16x8*)&T[n2][cg + 8];
}

// ---------------------------------------------------------------------------
// QKV GEMM v3 (m97 structure; q pre-scaled by QSCALE for exp2 domain).
// ---------------------------------------------------------------------------
__global__ __launch_bounds__(256) void qkv_mfma_kernel(
    const short* __restrict__ XT, const short* __restrict__ WQ,
    const float* __restrict__ gamma, const float* __restrict__ beta,
    const float* __restrict__ mean, const float* __restrict__ var,
    short* __restrict__ qT, short* __restrict__ kT, short* __restrict__ vb) {
  __shared__ __align__(16) unsigned short As[128 * 32];
  __shared__ __align__(16) unsigned short Bs[128 * 32];

  const int t = threadIdx.x, w = t >> 6, lane = t & 63;
  const int quad = lane >> 4, l16 = lane & 15;
  const int wr = w >> 1, wc = w & 1;
  const int ngt = blockIdx.x, h = blockIdx.y;
  const int o0 = h * 128, ng0 = ngt * 128;

  const int srow = lane >> 2;
  const int sseg = (lane & 3) * 8;

  f32x4 acc[4][4];
#pragma unroll
  for (int mi = 0; mi < 4; ++mi)
#pragma unroll
    for (int nj = 0; nj < 4; ++nj) { acc[mi][nj][0]=0.f; acc[mi][nj][1]=0.f; acc[mi][nj][2]=0.f; acc[mi][nj][3]=0.f; }

  for (int kt = 0; kt < 16; ++kt) {
    const int c0 = kt * 32;
    if (kt) __syncthreads();
#pragma unroll
    for (int r = 0; r < 2; ++r) {
      const int row = (r * 4 + w) * 16 + srow;
      gload_lds16(WQ + (size_t)(o0 + row) * 512 + c0 + sseg, As + (r * 4 + w) * 512);
      gload_lds16(XT + (size_t)(ng0 + row) * 512 + c0 + sseg, Bs + (r * 4 + w) * 512);
    }
    __syncthreads();
    bf16x8 af[4], bfr[4];
#pragma unroll
    for (int i = 0; i < 4; ++i) {
      af[i]  = *(const bf16x8*)&As[(wr * 64 + i * 16 + l16) * 32 + quad * 8];
      bfr[i] = *(const bf16x8*)&Bs[(wc * 64 + i * 16 + l16) * 32 + quad * 8];
    }
#pragma unroll
    for (int mi = 0; mi < 4; ++mi)
#pragma unroll
      for (int nj = 0; nj < 4; ++nj)
        acc[mi][nj] = __builtin_amdgcn_mfma_f32_16x16x32_bf16(af[mi], bfr[nj], acc[mi][nj], 0, 0, 0);
  }

  const int ng_base = ng0 + wc * 64;
#pragma unroll
  for (int mi = 0; mi < 4; ++mi) {
    const int ol = wr * 64 + mi * 16 + quad * 4;
    const int ob = o0 + ol;
    float inv[4], add[4];
#pragma unroll
    for (int r = 0; r < 4; ++r) {
      inv[r] = gamma[ob + r] * rsqrtf(var[ob + r] + EPS);
      add[r] = beta[ob + r] - mean[ob + r] * inv[r];
    }
    const int region = wr * 2 + (mi >> 1);   // 0=q, 1=k, 2/3=v
    if (region == 0) {
      const int kk = mi * 16 + quad * 4;
#pragma unroll
      for (int nj = 0; nj < 4; ++nj) {
        int ng = ng_base + nj * 16 + l16;
        int b = ng / 1600, n = ng - b * 1600;
        ushort4 u;
        u.x = f2bf((acc[mi][nj][0] * inv[0] + add[0]) * QSCALE);
        u.y = f2bf((acc[mi][nj][1] * inv[1] + add[1]) * QSCALE);
        u.z = f2bf((acc[mi][nj][2] * inv[2] + add[2]) * QSCALE);
        u.w = f2bf((acc[mi][nj][3] * inv[3] + add[3]) * QSCALE);
        *(ushort4*)&qT[((size_t)(b * 8 + h) * 1600 + n) * 32 + kk] = u;
      }
    } else if (region == 1) {
      const int kk = (mi - 2) * 16 + quad * 4;
#pragma unroll
      for (int nj = 0; nj < 4; ++nj) {
        int ng = ng_base + nj * 16 + l16;
        int b = ng / 1600, n = ng - b * 1600;
        ushort4 u;
        u.x = f2bf(acc[mi][nj][0] * inv[0] + add[0]);
        u.y = f2bf(acc[mi][nj][1] * inv[1] + add[1]);
        u.z = f2bf(acc[mi][nj][2] * inv[2] + add[2]);
        u.w = f2bf(acc[mi][nj][3] * inv[3] + add[3]);
        *(ushort4*)&kT[((size_t)(b * 8 + h) * 1600 + n) * 32 + kk] = u;
      }
    } else {
      const int ch = h * 64 + (ol - 64);
#pragma unroll
      for (int nj = 0; nj < 4; ++nj) {
        int ng = ng_base + nj * 16 + l16;
        int b = ng / 1600, n = ng - b * 1600;
#pragma unroll
        for (int r = 0; r < 4; ++r)
          ((unsigned short*)vb)[((size_t)(b * 512 + ch + r)) * 1600 + n] =
              f2bf(acc[mi][nj][r] * inv[r] + add[r]);
      }
    }
  }
}

// ---------------------------------------------------------------------------
// MFMA flash attention v5: raw v_exp_f32 (exp2 domain, q pre-scaled),
// v_perm P-packing, bf16 y output. S^T layout, double-buffered P, 1 barrier
// per m-tile, grid.x = bh.
// ---------------------------------------------------------------------------
__global__ __launch_bounds__(256) void attn_mfma_kernel(
    const short* __restrict__ qT, const short* __restrict__ kT,
    const short* __restrict__ vb, short* __restrict__ ybf) {
  const int N = 1600;
  const int PS = 72;
  __shared__ __align__(16) unsigned short Plds[2][64 * PS];
  __shared__ float den_lds[4][64];
  __shared__ float rden[64];

  const int t = threadIdx.x;
  const int w = t >> 6, lane = t & 63, quad = lane >> 4, l16 = lane & 15;
  const int bh = blockIdx.x, b = bh >> 3, h = bh & 7;
  const int n0 = blockIdx.y * 64;

  const short* qTb = qT + (size_t)(b * 8 + h) * N * 32;
  const short* kTb = kT + (size_t)(b * 8 + h) * N * 32;
  const short* vbb = vb + ((size_t)b * 512 + h * 64 + w * 16) * N;

  bf16x8 qf[4];
#pragma unroll
  for (int i = 0; i < 4; ++i)
    qf[i] = *(const bf16x8*)(qTb + (size_t)(n0 + i * 16 + l16) * 32 + quad * 8);

  f32x4 acc[4];
#pragma unroll
  for (int i = 0; i < 4; ++i) { acc[i][0]=0.f; acc[i][1]=0.f; acc[i][2]=0.f; acc[i][3]=0.f; }
  float den[4] = {0.f, 0.f, 0.f, 0.f};
  const f32x4 zero4 = {0.f, 0.f, 0.f, 0.f};

#pragma unroll 2
  for (int mt = 0; mt < 25; ++mt) {
    const int m0 = mt * 64;
    unsigned short* Pb = &Plds[mt & 1][0];
    bf16x8 kf = *(const bf16x8*)(kTb + (size_t)(m0 + w * 16 + l16) * 32 + quad * 8);
#pragma unroll
    for (int i = 0; i < 4; ++i) {
      f32x4 s = __builtin_amdgcn_mfma_f32_16x16x32_bf16(kf, qf[i], zero4, 0, 0, 0);
      float p0 = fexp2(s[0]), p1 = fexp2(s[1]), p2 = fexp2(s[2]), p3 = fexp2(s[3]);
      den[i] += (p0 + p1) + (p2 + p3);
      uint2 pk;
      pk.x = pack_bf_trunc(p0, p1);
      pk.y = pack_bf_trunc(p2, p3);
      *(uint2*)&Pb[(size_t)(i * 16 + l16) * PS + w * 16 + quad * 4] = pk;
    }
    __syncthreads();
#pragma unroll
    for (int c = 0; c < 2; ++c) {
      bf16x8 vfr = *(const bf16x8*)(vbb + (size_t)l16 * N + m0 + c * 32 + quad * 8);
#pragma unroll
      for (int i = 0; i < 4; ++i) {
        bf16x8 pf = *(const bf16x8*)(Pb + (size_t)(i * 16 + l16) * PS + c * 32 + quad * 8);
        acc[i] = __builtin_amdgcn_mfma_f32_16x16x32_bf16(pf, vfr, acc[i], 0, 0, 0);
      }
    }
  }

#pragma unroll
  for (int i = 0; i < 4; ++i) {
    den[i] += __shfl_xor(den[i], 16, 64);
    den[i] += __shfl_xor(den[i], 32, 64);
  }
  if (quad == 0) {
#pragma unroll
    for (int i = 0; i < 4; ++i)
      den_lds[w][i * 16 + l16] = den[i];
  }
  __syncthreads();
  if (t < 64)
    rden[t] = 1.f / (den_lds[0][t] + den_lds[1][t] + den_lds[2][t] + den_lds[3][t]);
  __syncthreads();

  unsigned short* yr = (unsigned short*)ybf +
      ((size_t)b * 512 + h * 64 + w * 16 + l16) * N + n0;
#pragma unroll
  for (int i = 0; i < 4; ++i) {
    const int nb = i * 16 + quad * 4;
    ushort4 o4;
    o4.x = f2bf(acc[i][0] * rden[nb + 0]);
    o4.y = f2bf(acc[i][1] * rden[nb + 1]);
    o4.z = f2bf(acc[i][2] * rden[nb + 2]);
    o4.w = f2bf(acc[i][3] * rden[nb + 3]);
    *(ushort4*)&yr[nb] = o4;
  }
}

// ---------------------------------------------------------------------------
// PE v4 (unchanged): bf16 y in, LDS-staged dw3x3 + BN + add, bf16 out.
// ---------------------------------------------------------------------------
__global__ __launch_bounds__(256) void pe_kernel(
    const short* __restrict__ Ybf, const short* __restrict__ VB,
    const float* __restrict__ pw,
    const float* __restrict__ gamma, const float* __restrict__ beta,
    const float* __restrict__ mean, const float* __restrict__ var,
    short* __restrict__ YB) {
  __shared__ __align__(16) unsigned short V[4 * 42 * 56];
  __shared__ float wlds[36];
  __shared__ float invs[4], adds[4];

  const int t = threadIdx.x;
  const int b = blockIdx.y, c0 = blockIdx.x * 4;

  const u16x8 z = {0, 0, 0, 0, 0, 0, 0, 0};
  for (int k = t; k < 1176; k += 256)
    *(u16x8*)&V[k * 8] = z;
  if (t < 36) wlds[t] = pw[c0 * 9 + t];
  if (t < 4) {
    int c = c0 + t;
    float inv = gamma[c] * rsqrtf(var[c] + EPS);
    invs[t] = inv;
    adds[t] = beta[c] - mean[c] * inv;
  }
  __syncthreads();

  for (int u = t; u < 800; u += 256) {
    int ch = u / 200, j = u - ch * 200;
    int row = j / 5, col8 = (j - row * 5) * 8;
    u16x8 d = *(const u16x8*)((const unsigned short*)VB +
        ((size_t)(b * 512 + c0 + ch) * 1600 + row * 40 + col8));
    *(u16x8*)&V[ch * 2352 + (row + 1) * 56 + 8 + col8] = d;
  }
  __syncthreads();

#pragma unroll 1
  for (int k = 0; k < 25; ++k) {
    int o = k * 256 + t;
    int ch = o / 1600, n = o - ch * 1600;
    int hh = n / 40, ww = n - hh * 40;
    const unsigned short* Vc = &V[ch * 2352 + (hh + 1) * 56 + 8 + ww];
    const float* wk = &wlds[ch * 9];
    float s = 0.f;
#pragma unroll
    for (int dy = 0; dy < 3; ++dy)
#pragma unroll
      for (int dx = 0; dx < 3; ++dx)
        s += wk[dy * 3 + dx] * bf2f(Vc[(dy - 1) * 56 + (dx - 1)]);
    size_t idx = (size_t)(b * 512 + c0 + ch) * 1600 + n;
    float val = bf2f(((const unsigned short*)Ybf)[idx]) + s * invs[ch] + adds[ch];
    YB[idx] = (short)f2bf(val);
  }
}

// ---------------------------------------------------------------------------
// Proj GEMM v3 (m97 structure, unchanged).
// ---------------------------------------------------------------------------
__global__ __launch_bounds__(256) void proj_mfma_kernel(
    const short* __restrict__ YT, const short* __restrict__ WP,
    const float* __restrict__ gamma, const float* __restrict__ beta,
    const float* __restrict__ mean, const float* __restrict__ var,
    float* __restrict__ OUT) {
  __shared__ __align__(16) unsigned short As[64 * 32];
  __shared__ __align__(16) unsigned short Bs[128 * 32];

  const int t = threadIdx.x, w = t >> 6, lane = t & 63;
  const int quad = lane >> 4, l16 = lane & 15;
  const int wr = w >> 1, wc = w & 1;
  const int ngt = blockIdx.x;
  const int o0 = blockIdx.y * 64;
  const int ng0 = ngt * 128;

  const int srow = lane >> 2;
  const int sseg = (lane & 3) * 8;

  f32x4 acc[2][4];
#pragma unroll
  for (int mi = 0; mi < 2; ++mi)
#pragma unroll
    for (int nj = 0; nj < 4; ++nj) { acc[mi][nj][0]=0.f; acc[mi][nj][1]=0.f; acc[mi][nj][2]=0.f; acc[mi][nj][3]=0.f; }

  for (int kt = 0; kt < 16; ++kt) {
    const int c0 = kt * 32;
    if (kt) __syncthreads();
    {
      const int row = w * 16 + srow;
      gload_lds16(WP + (size_t)(o0 + row) * 512 + c0 + sseg, As + w * 512);
    }
#pragma unroll
    for (int r = 0; r < 2; ++r) {
      const int row = (r * 4 + w) * 16 + srow;
      gload_lds16(YT + (size_t)(ng0 + row) * 512 + c0 + sseg, Bs + (r * 4 + w) * 512);
    }
    __syncthreads();
    bf16x8 af[2], bfr[4];
#pragma unroll
    for (int i = 0; i < 2; ++i)
      af[i] = *(const bf16x8*)&As[(wr * 32 + i * 16 + l16) * 32 + quad * 8];
#pragma unroll
    for (int i = 0; i < 4; ++i)
      bfr[i] = *(const bf16x8*)&Bs[(wc * 64 + i * 16 + l16) * 32 + quad * 8];
#pragma unroll
    for (int mi = 0; mi < 2; ++mi)
#pragma unroll
      for (int nj = 0; nj < 4; ++nj)
        acc[mi][nj] = __builtin_amdgcn_mfma_f32_16x16x32_bf16(af[mi], bfr[nj], acc[mi][nj], 0, 0, 0);
  }

  const int ng_base = ng0 + wc * 64;
#pragma unroll
  for (int mi = 0; mi < 2; ++mi) {
    const int ob = o0 + wr * 32 + mi * 16 + quad * 4;
    float inv[4], add[4];
#pragma unroll
    for (int r = 0; r < 4; ++r) {
      inv[r] = gamma[ob + r] * rsqrtf(var[ob + r] + EPS);
      add[r] = beta[ob + r] - mean[ob + r] * inv[r];
    }
#pragma unroll
    for (int nj = 0; nj < 4; ++nj) {
      int ng = ng_base + nj * 16 + l16;
      int b = ng / 1600, n = ng - b * 1600;
#pragma unroll
      for (int r = 0; r < 4; ++r)
        OUT[((size_t)(b * 512 + ob + r)) * 1600 + n] = acc[mi][nj][r] * inv[r] + add[r];
    }
  }
}

// ---------------------------------------------------------------------------
extern "C" void kernel_launch(void* const* d_in, const int* in_sizes, int n_in,
                              void* d_out, int out_size, void* d_ws, size_t ws_size,
                              hipStream_t stream) {
  const float* x          = (const float*)d_in[0];
  const float* qkv_w      = (const float*)d_in[1];
  const float* qkv_gamma  = (const float*)d_in[2];
  const float* qkv_beta   = (const float*)d_in[3];
  const float* qkv_mean   = (const float*)d_in[4];
  const float* qkv_var    = (const float*)d_in[5];
  const float* pe_w       = (const float*)d_in[6];
  const float* pe_gamma   = (const float*)d_in[7];
  const float* pe_beta    = (const float*)d_in[8];
  const float* pe_mean    = (const float*)d_in[9];
  const float* pe_var     = (const float*)d_in[10];
  const float* proj_w     = (const float*)d_in[11];
  const float* proj_gamma = (const float*)d_in[12];
  const float* proj_beta  = (const float*)d_in[13];
  const float* proj_mean  = (const float*)d_in[14];
  const float* proj_var   = (const float*)d_in[15];
  float* out = (float*)d_out;

  float* ws_a = (float*)d_ws;
  short* ybf_attn = (short*)d_ws;
  short* qT   = (short*)(ws_a + (size_t)6553600);
  short* kT   = qT + (size_t)3276800;
  short* vb   = kT + (size_t)3276800;
  short* xT   = vb + (size_t)6553600;
  short* wq   = xT + (size_t)6553600;
  short* wp   = wq + (size_t)524288;
  short* yT   = xT;
  short* ybf_pe = qT;

  cast_w_kernel<<<768, 256, 0, stream>>>(qkv_w, proj_w, wq, wp);
  {
    dim3 grid(8, 25, 8), block(256);
    transpose_cast_kernel<<<grid, block, 0, stream>>>(x, xT);
  }
  {
    dim3 grid(100, 8), block(256);
    qkv_mfma_kernel<<<grid, block, 0, stream>>>(
        xT, wq, qkv_gamma, qkv_beta, qkv_mean, qkv_var, qT, kT, vb);
  }
  {
    dim3 grid(64, 25), block(256);
    attn_mfma_kernel<<<grid, block, 0, stream>>>(qT, kT, vb, ybf_attn);
  }
  {
    dim3 grid(128, 8), block(256);
    pe_kernel<<<grid, block, 0, stream>>>(
        ybf_attn, vb, pe_w, pe_gamma, pe_beta, pe_mean, pe_var, ybf_pe);
  }
  {
    dim3 grid(8, 25, 8), block(256);
    transpose16_kernel<<<grid, block, 0, stream>>>(ybf_pe, yT);
  }
  {
    dim3 grid(100, 8), block(256);
    proj_mfma_kernel<<<grid, block, 0, stream>>>(
        yT, wp, proj_gamma, proj_beta, proj_mean, proj_var, out);
  }
}